// Round 18
// baseline (71.566 us; speedup 1.0000x reference)
//
#include <hip/hip_runtime.h>
#include <hip/hip_bf16.h>

typedef short  bf16x8 __attribute__((ext_vector_type(8)));
typedef float  f32x4  __attribute__((ext_vector_type(4)));

#define WROWS 22            // 16 output rows + 6 halo
#define WSTR  72            // ushorts per row (144 B, 16B-multiple)
#define WPAD  8             // lane63/jo3 b128 overrun: must be zeroed, finite
#define WSZ   (WROWS * WSTR + WPAD)   // 1592 ushorts = 3184 B
#define NCHW  18            // float4 chunks per row
#define CHTW  (WROWS * NCHW)          // 396 chunks per wave-tile

static __device__ __forceinline__ unsigned int rne16(float f) {
    unsigned int u = __float_as_uint(f);
    return (u + 0x7FFFu + ((u >> 16) & 1u)) >> 16;   // fp32 -> bf16 RNE
}

// Pack float2 -> 2xbf16 via v_cvt_pk_bf16_f32 (compiler cast path, RNE)
static __device__ __forceinline__ unsigned int pkbf16(float a, float b) {
    __hip_bfloat162 h = __float22bfloat162_rn(make_float2(a, b));
    return *reinterpret_cast<unsigned int*>(&h);
}

// ---- Setup: banded-B fragments once into ws (7 dy x 64 lanes x 16B) ----
// B[u][j] = w[dy][u-j-1]; rows u >= 23 structurally zero (kills A-read wrap).
__global__ void build_bfrag(const float* __restrict__ w, bf16x8* __restrict__ ws) {
    const int l   = threadIdx.x;      // 64 threads
    const int l15 = l & 15;
    const int u0  = (l >> 4) * 8;
#pragma unroll
    for (int dy = 0; dy < 7; ++dy) {
        union { unsigned int u[4]; bf16x8 v; } bb;
#pragma unroll
        for (int qp = 0; qp < 4; ++qp) {
            unsigned int half[2];
#pragma unroll
            for (int h = 0; h < 2; ++h) {
                const int d = u0 + qp * 2 + h - l15 - 1;     // weight col dx
                const float val = (d >= 0 && d < 7) ? w[dy * 7 + d] : 0.f;
                half[h] = rne16(val);
            }
            bb.u[qp] = half[0] | (half[1] << 16);
        }
        ws[dy * 64 + l] = bb.v;
    }
}

// ---- Main: barrier-free wave-private LDS, 2 tiles/wave through one buffer.
// Staging convert: v_cvt_pk_bf16_f32 (1 inst / 2 elems, was ~8).
// Output stores nontemporal: don't evict the L3-resident input. ----
__global__ __launch_bounds__(256)
void conv7x7_mfma(const float* __restrict__ x, const bf16x8* __restrict__ Bws,
                  float* __restrict__ out) {
    __shared__ unsigned short lds[4][WSZ];   // 12736 B/block

    const int W = 512, H = 512;
    // XCD-aware bijective swizzle (4096 % 8 == 0)
    const int raw = blockIdx.x;
    const int bi  = (raw & 7) * 512 + (raw >> 3);
    const int n   = bi >> 5;             // n(7) | ty(3) | gx(2)
    const int ty  = (bi >> 2) & 7;
    const int gx  = bi & 3;

    const float* xn = x + (size_t)n * (H * W);
    float*       on = out + (size_t)n * (H * W);

    const int t   = threadIdx.x;
    const int l   = t & 63;
    const int wv  = t >> 6;
    const int l15 = l & 15;
    const int lk  = l >> 4;
    const int u0  = lk * 8;

    const int y0  = ty * 64 + wv * 16;   // wave's output rows y0..y0+15
    const int x0g = gx * 128;            // two tiles: x0g, x0g+64

    unsigned short* my = lds[wv];        // wave-private region

    // Zero the pad (wave-private read-only wrap region)
    if (l < WPAD) my[WROWS * WSTR + l] = 0;

    // Prebuilt B fragments (L2-resident broadcast)
    bf16x8 Bf[7];
#pragma unroll
    for (int dy = 0; dy < 7; ++dy) Bf[dy] = Bws[dy * 64 + l];

    // k-invariant staging descriptors (7 chunks/lane per tile)
    int  d_roff[7], d_loff[7], d_xoff[7];
    bool d_rok[7], d_act[7];
#pragma unroll
    for (int it = 0; it < 7; ++it) {
        const int idx = l + 64 * it;
        const int r   = idx / NCHW;
        const int cc  = idx - r * NCHW;
        const int gr  = y0 - 3 + r;
        d_act[it]  = (idx < CHTW);
        d_rok[it]  = d_act[it] && (gr >= 0) && (gr < H);
        d_xoff[it] = x0g - 4 + 4 * cc;
        d_roff[it] = gr * W;
        d_loff[it] = r * WSTR + 4 * cc;
    }

    float4 sregA[7], sregB[7];

#define ISSUE(SR, k_)                                                          \
    {                                                                          \
        _Pragma("unroll")                                                      \
        for (int it = 0; it < 7; ++it) {                                       \
            const int gc = d_xoff[it] + 64 * (k_);                             \
            float4 v = make_float4(0.f, 0.f, 0.f, 0.f);                        \
            if (d_rok[it] && gc >= 0 && gc <= W - 4)                           \
                v = *reinterpret_cast<const float4*>(&xn[d_roff[it] + gc]);    \
            SR[it] = v;                                                        \
        }                                                                      \
    }

#define LDSWRITE(SR)                                                           \
    {                                                                          \
        _Pragma("unroll")                                                      \
        for (int it = 0; it < 7; ++it) {                                       \
            if (d_act[it]) {                                                   \
                const unsigned p0 = pkbf16(SR[it].x, SR[it].y);                \
                const unsigned p1 = pkbf16(SR[it].z, SR[it].w);                \
                *reinterpret_cast<uint2*>(&my[d_loff[it]]) =                   \
                    make_uint2(p0, p1);                                        \
            }                                                                  \
        }                                                                      \
    }

#define COMPUTE(k_)                                                            \
    {                                                                          \
        const int xk = x0g + 64 * (k_);                                        \
        _Pragma("unroll")                                                      \
        for (int jo = 0; jo < 4; ++jo) {                                       \
            f32x4 acc = {0.f, 0.f, 0.f, 0.f};                                  \
            _Pragma("unroll")                                                  \
            for (int dy = 0; dy < 7; ++dy) {                                   \
                const int row = l15 + dy;                                      \
                const bf16x8 a = *reinterpret_cast<const bf16x8*>(             \
                    &my[row * WSTR + jo * 16 + u0]);                           \
                acc = __builtin_amdgcn_mfma_f32_16x16x32_bf16(a, Bf[dy], acc,  \
                                                              0, 0, 0);        \
            }                                                                  \
            _Pragma("unroll")                                                  \
            for (int rr = 0; rr < 4; ++rr) {                                   \
                const int gr = y0 + lk * 4 + rr;                               \
                __builtin_nontemporal_store(                                   \
                    acc[rr], &on[(size_t)gr * W + xk + jo * 16 + l15]);        \
            }                                                                  \
        }                                                                      \
    }

    // Pipeline: both tiles' loads issued up front (14 in flight); counted
    // vmcnt (no barriers) lets tile-1 loads fly over write(0)+compute(0).
    ISSUE(sregA, 0)
    ISSUE(sregB, 1)
    LDSWRITE(sregA)
    COMPUTE(0)
    LDSWRITE(sregB)
    COMPUTE(1)

#undef ISSUE
#undef LDSWRITE
#undef COMPUTE
}

extern "C" void kernel_launch(void* const* d_in, const int* in_sizes, int n_in,
                              void* d_out, int out_size, void* d_ws, size_t ws_size,
                              hipStream_t stream) {
    const float* x = (const float*)d_in[0];
    const float* w = (const float*)d_in[1];
    float* out = (float*)d_out;
    bf16x8* bws = (bf16x8*)d_ws;

    build_bfrag<<<1, 64, 0, stream>>>(w, bws);

    const int nblocks = 128 * 8 * 4;   // 4096 blocks x 256 threads (4 waves)
    conv7x7_mfma<<<nblocks, 256, 0, stream>>>(x, bws, out);
}

// Round 19
// 65.323 us; speedup vs baseline: 1.0956x; 1.0956x over previous
//
#include <hip/hip_runtime.h>
#include <hip/hip_bf16.h>

typedef short  bf16x8 __attribute__((ext_vector_type(8)));
typedef float  f32x4  __attribute__((ext_vector_type(4)));

#define WROWS 22            // 16 output rows + 6 halo
#define WSTR  72            // ushorts per row (144 B, 16B-multiple)
#define WPAD  8             // lane63/jo3 b128 overrun: must be zeroed, finite
#define WSZ   (WROWS * WSTR + WPAD)   // 1592 ushorts = 3184 B
#define NCHW  18            // float4 chunks per row
#define CHTW  (WROWS * NCHW)          // 396 chunks per wave-tile

static __device__ __forceinline__ unsigned int rne16(float f) {
    unsigned int u = __float_as_uint(f);
    return (u + 0x7FFFu + ((u >> 16) & 1u)) >> 16;   // fp32 -> bf16 RNE
}

// Pack float2 -> 2xbf16 (v_cvt_pk_bf16_f32 via compiler cast path, RNE)
static __device__ __forceinline__ unsigned int pkbf16(float a, float b) {
    __hip_bfloat162 h = __float22bfloat162_rn(make_float2(a, b));
    return *reinterpret_cast<unsigned int*>(&h);
}

// ---- Setup: banded-B fragments once into ws (7 dy x 64 lanes x 16B) ----
// B[u][j] = w[dy][u-j-1]; rows u >= 23 structurally zero (kills A-read wrap).
__global__ void build_bfrag(const float* __restrict__ w, bf16x8* __restrict__ ws) {
    const int l   = threadIdx.x;      // 64 threads
    const int l15 = l & 15;
    const int u0  = (l >> 4) * 8;
#pragma unroll
    for (int dy = 0; dy < 7; ++dy) {
        union { unsigned int u[4]; bf16x8 v; } bb;
#pragma unroll
        for (int qp = 0; qp < 4; ++qp) {
            unsigned int half[2];
#pragma unroll
            for (int h = 0; h < 2; ++h) {
                const int d = u0 + qp * 2 + h - l15 - 1;     // weight col dx
                const float val = (d >= 0 && d < 7) ? w[dy * 7 + d] : 0.f;
                half[h] = rne16(val);
            }
            bb.u[qp] = half[0] | (half[1] << 16);
        }
        ws[dy * 64 + l] = bb.v;
    }
}

// ---- Main: barrier-free wave-private LDS, 2 tiles/wave through one buffer.
// Staging convert: v_cvt_pk_bf16_f32 (2 insts/chunk, was ~8).
// Stores: NORMAL cached (R18 showed nontemporal scalar stores cause
// partial-line write amplification: WRITE 131 -> 188 MB, +47% dur). ----
__global__ __launch_bounds__(256)
void conv7x7_mfma(const float* __restrict__ x, const bf16x8* __restrict__ Bws,
                  float* __restrict__ out) {
    __shared__ unsigned short lds[4][WSZ];   // 12736 B/block

    const int W = 512, H = 512;
    // XCD-aware bijective swizzle (4096 % 8 == 0)
    const int raw = blockIdx.x;
    const int bi  = (raw & 7) * 512 + (raw >> 3);
    const int n   = bi >> 5;             // n(7) | ty(3) | gx(2)
    const int ty  = (bi >> 2) & 7;
    const int gx  = bi & 3;

    const float* xn = x + (size_t)n * (H * W);
    float*       on = out + (size_t)n * (H * W);

    const int t   = threadIdx.x;
    const int l   = t & 63;
    const int wv  = t >> 6;
    const int l15 = l & 15;
    const int lk  = l >> 4;
    const int u0  = lk * 8;

    const int y0  = ty * 64 + wv * 16;   // wave's output rows y0..y0+15
    const int x0g = gx * 128;            // two tiles: x0g, x0g+64

    unsigned short* my = lds[wv];        // wave-private region

    // Zero the pad (wave-private read-only wrap region)
    if (l < WPAD) my[WROWS * WSTR + l] = 0;

    // Prebuilt B fragments (L2-resident broadcast)
    bf16x8 Bf[7];
#pragma unroll
    for (int dy = 0; dy < 7; ++dy) Bf[dy] = Bws[dy * 64 + l];

    // k-invariant staging descriptors (7 chunks/lane per tile)
    int  d_roff[7], d_loff[7], d_xoff[7];
    bool d_rok[7], d_act[7];
#pragma unroll
    for (int it = 0; it < 7; ++it) {
        const int idx = l + 64 * it;
        const int r   = idx / NCHW;
        const int cc  = idx - r * NCHW;
        const int gr  = y0 - 3 + r;
        d_act[it]  = (idx < CHTW);
        d_rok[it]  = d_act[it] && (gr >= 0) && (gr < H);
        d_xoff[it] = x0g - 4 + 4 * cc;
        d_roff[it] = gr * W;
        d_loff[it] = r * WSTR + 4 * cc;
    }

    float4 sregA[7], sregB[7];

#define ISSUE(SR, k_)                                                          \
    {                                                                          \
        _Pragma("unroll")                                                      \
        for (int it = 0; it < 7; ++it) {                                       \
            const int gc = d_xoff[it] + 64 * (k_);                             \
            float4 v = make_float4(0.f, 0.f, 0.f, 0.f);                        \
            if (d_rok[it] && gc >= 0 && gc <= W - 4)                           \
                v = *reinterpret_cast<const float4*>(&xn[d_roff[it] + gc]);    \
            SR[it] = v;                                                        \
        }                                                                      \
    }

#define LDSWRITE(SR)                                                           \
    {                                                                          \
        _Pragma("unroll")                                                      \
        for (int it = 0; it < 7; ++it) {                                       \
            if (d_act[it]) {                                                   \
                const unsigned p0 = pkbf16(SR[it].x, SR[it].y);                \
                const unsigned p1 = pkbf16(SR[it].z, SR[it].w);                \
                *reinterpret_cast<uint2*>(&my[d_loff[it]]) =                   \
                    make_uint2(p0, p1);                                        \
            }                                                                  \
        }                                                                      \
    }

#define COMPUTE(k_)                                                            \
    {                                                                          \
        const int xk = x0g + 64 * (k_);                                        \
        _Pragma("unroll")                                                      \
        for (int jo = 0; jo < 4; ++jo) {                                       \
            f32x4 acc = {0.f, 0.f, 0.f, 0.f};                                  \
            _Pragma("unroll")                                                  \
            for (int dy = 0; dy < 7; ++dy) {                                   \
                const int row = l15 + dy;                                      \
                const bf16x8 a = *reinterpret_cast<const bf16x8*>(             \
                    &my[row * WSTR + jo * 16 + u0]);                           \
                acc = __builtin_amdgcn_mfma_f32_16x16x32_bf16(a, Bf[dy], acc,  \
                                                              0, 0, 0);        \
            }                                                                  \
            _Pragma("unroll")                                                  \
            for (int rr = 0; rr < 4; ++rr) {                                   \
                const int gr = y0 + lk * 4 + rr;                               \
                on[(size_t)gr * W + xk + jo * 16 + l15] = acc[rr];             \
            }                                                                  \
        }                                                                      \
    }

    // Pipeline: both tiles' loads issued up front (14 in flight); counted
    // vmcnt (no barriers) lets tile-1 loads fly over write(0)+compute(0).
    ISSUE(sregA, 0)
    ISSUE(sregB, 1)
    LDSWRITE(sregA)
    COMPUTE(0)
    LDSWRITE(sregB)
    COMPUTE(1)

#undef ISSUE
#undef LDSWRITE
#undef COMPUTE
}

extern "C" void kernel_launch(void* const* d_in, const int* in_sizes, int n_in,
                              void* d_out, int out_size, void* d_ws, size_t ws_size,
                              hipStream_t stream) {
    const float* x = (const float*)d_in[0];
    const float* w = (const float*)d_in[1];
    float* out = (float*)d_out;
    bf16x8* bws = (bf16x8*)d_ws;

    build_bfrag<<<1, 64, 0, stream>>>(w, bws);

    const int nblocks = 128 * 8 * 4;   // 4096 blocks x 256 threads (4 waves)
    conv7x7_mfma<<<nblocks, 256, 0, stream>>>(x, bws, out);
}

// Round 20
// 49.928 us; speedup vs baseline: 1.4334x; 1.3083x over previous
//
#include <hip/hip_runtime.h>

typedef short  bf16x8 __attribute__((ext_vector_type(8)));
typedef float  f32x4  __attribute__((ext_vector_type(4)));

#define WROWS 38            // 32 output rows + 6 halo
#define WSTR  72            // ushorts per row (144 B, 16B-multiple)
#define WPAD  8             // lane63/jo3 b128 overrun: must be zeroed, finite
#define WSZ   (WROWS * WSTR + WPAD)   // 2744 ushorts = 5488 B
#define NCHW  18            // float4 chunks per row
#define CHTW  (WROWS * NCHW)          // 684 chunks per wave-tile
#define NIT   11            // ceil(684 / 64)

static __device__ __forceinline__ unsigned int rne16(float f) {
    unsigned int u = __float_as_uint(f);
    return (u + 0x7FFFu + ((u >> 16) & 1u)) >> 16;   // fp32 -> bf16 RNE
}

// ---- Setup: banded-B fragments once into ws (7 dy x 64 lanes x 16B) ----
// B[u][j] = w[dy][u-j-1]; rows u >= 23 structurally zero (kills A-read wrap).
__global__ void build_bfrag(const float* __restrict__ w, bf16x8* __restrict__ ws) {
    const int l   = threadIdx.x;      // 64 threads
    const int l15 = l & 15;
    const int u0  = (l >> 4) * 8;
#pragma unroll
    for (int dy = 0; dy < 7; ++dy) {
        union { unsigned int u[4]; bf16x8 v; } bb;
#pragma unroll
        for (int qp = 0; qp < 4; ++qp) {
            unsigned int half[2];
#pragma unroll
            for (int h = 0; h < 2; ++h) {
                const int d = u0 + qp * 2 + h - l15 - 1;     // weight col dx
                const float val = (d >= 0 && d < 7) ? w[dy * 7 + d] : 0.f;
                half[h] = rne16(val);
            }
            bb.u[qp] = half[0] | (half[1] << 16);
        }
        ws[dy * 64 + l] = bb.v;
    }
}

// ---- Main: barrier-free wave-private LDS; 32 output rows per wave
// (38-row window; halo amplification 1.19x vs 1.375x at 16 rows).
// Per jo: two stacked 16x16 D-tiles (rows +0 / +16), 14 MFMAs. ----
__global__ __launch_bounds__(256)
void conv7x7_mfma(const float* __restrict__ x, const bf16x8* __restrict__ Bws,
                  float* __restrict__ out) {
    __shared__ unsigned short lds[4][WSZ];   // 21952 B/block -> 7 blocks/CU

    const int W = 512, H = 512;
    // XCD-aware bijective swizzle (4096 % 8 == 0)
    const int raw = blockIdx.x;
    const int bi  = (raw & 7) * 512 + (raw >> 3);
    const int n   = bi >> 5;             // n(7) | by(2) | tx(3)
    const int rem = bi & 31;
    const int by  = rem >> 3;            // 0..3 (128-row block band)
    const int tx  = rem & 7;

    const float* xn = x + (size_t)n * (H * W);
    float*       on = out + (size_t)n * (H * W);

    const int t   = threadIdx.x;
    const int l   = t & 63;
    const int wv  = t >> 6;
    const int l15 = l & 15;
    const int lk  = l >> 4;
    const int u0  = lk * 8;

    const int y0 = by * 128 + wv * 32;   // wave's output rows y0..y0+31
    const int x0 = tx * 64;              // wave's output cols x0..x0+63

    unsigned short* my = lds[wv];        // wave-private region

    // Zero the pad (wave-private read-only wrap region)
    if (l < WPAD) my[WROWS * WSTR + l] = 0;

    // Prebuilt B fragments (L2-resident broadcast)
    bf16x8 Bf[7];
#pragma unroll
    for (int dy = 0; dy < 7; ++dy) Bf[dy] = Bws[dy * 64 + l];

    // ---- Stage the wave's 38x72 window: fp32 -> bf16(RNE), one burst ----
    float4 sreg[NIT];
    int    loff[NIT];
    bool   act[NIT];
#pragma unroll
    for (int it = 0; it < NIT; ++it) {
        const int idx = l + 64 * it;
        const int r   = idx / NCHW;
        const int cc  = idx - r * NCHW;
        const int gr  = y0 - 3 + r;
        const int gc  = x0 - 4 + 4 * cc;   // 16B-aligned, full-or-zero OOB
        act[it]  = (idx < CHTW);
        loff[it] = r * WSTR + 4 * cc;
        float4 v = make_float4(0.f, 0.f, 0.f, 0.f);
        if (act[it] && gr >= 0 && gr < H && gc >= 0 && gc <= W - 4)
            v = *reinterpret_cast<const float4*>(&xn[(size_t)gr * W + gc]);
        sreg[it] = v;
    }
#pragma unroll
    for (int it = 0; it < NIT; ++it) {
        if (act[it]) {
            const unsigned p0 = rne16(sreg[it].x) | (rne16(sreg[it].y) << 16);
            const unsigned p1 = rne16(sreg[it].z) | (rne16(sreg[it].w) << 16);
            *reinterpret_cast<uint2*>(&my[loff[it]]) = make_uint2(p0, p1);
        }
    }
    // same-wave ds_write -> ds_read ordering via compiler lgkmcnt; no barrier

    // ---- Compute: 4 jo-columns x 2 stacked 16x16 tiles, 7 MFMAs each ----
#pragma unroll
    for (int jo = 0; jo < 4; ++jo) {
        f32x4 aLo = {0.f, 0.f, 0.f, 0.f};
        f32x4 aHi = {0.f, 0.f, 0.f, 0.f};
#pragma unroll
        for (int dy = 0; dy < 7; ++dy) {
            const int rowL = l15 + dy;                    // outputs y0..y0+15
            const bf16x8 aL = *reinterpret_cast<const bf16x8*>(
                &my[rowL * WSTR + jo * 16 + u0]);
            aLo = __builtin_amdgcn_mfma_f32_16x16x32_bf16(aL, Bf[dy], aLo, 0, 0, 0);
            const bf16x8 aH = *reinterpret_cast<const bf16x8*>(
                &my[(rowL + 16) * WSTR + jo * 16 + u0]);  // outputs +16
            aHi = __builtin_amdgcn_mfma_f32_16x16x32_bf16(aH, Bf[dy], aHi, 0, 0, 0);
        }
#pragma unroll
        for (int rr = 0; rr < 4; ++rr) {
            const int gr = y0 + lk * 4 + rr;
            on[(size_t)gr * W + x0 + jo * 16 + l15] = aLo[rr];
            on[(size_t)(gr + 16) * W + x0 + jo * 16 + l15] = aHi[rr];
        }
    }
}

extern "C" void kernel_launch(void* const* d_in, const int* in_sizes, int n_in,
                              void* d_out, int out_size, void* d_ws, size_t ws_size,
                              hipStream_t stream) {
    const float* x = (const float*)d_in[0];
    const float* w = (const float*)d_in[1];
    float* out = (float*)d_out;
    bf16x8* bws = (bf16x8*)d_ws;

    build_bfrag<<<1, 64, 0, stream>>>(w, bws);

    const int nblocks = 128 * 4 * 8;   // 4096 blocks x 256 threads (4 waves)
    conv7x7_mfma<<<nblocks, 256, 0, stream>>>(x, bws, out);
}